// Round 5
// baseline (62.037 us; speedup 1.0000x reference)
//
#include <hip/hip_runtime.h>

// SudokuUniqueHVBox (type='h'), bit-domain, WAVE-SYNCHRONOUS (no barriers,
// no atomics). Each wave owns 4 whole batches = 2916 floats = 729 f4 exactly:
//   1) 12 coalesced b128 loads -> 4-bit masks -> plain byte writes to a
//      wave-private LDS nibble array (cross-LANE sharing only, so wave
//      lockstep + lgkmcnt ordering suffices -> no __syncthreads).
//   2) lanes 0..35: unit (bl,h): 9 rows, each from exactly 3 nibbles
//      (win = B0>>a | B1<<(4-a) | B2<<(8-a), a=9r&3); popc==1 -> uniq;
//      covered = OR uniq rows; out = uniq ? row : row & ~covered.
//   3) all lanes: expand 12 f4 from 2 row words each, nt store to global.
// Exact vs float reference (inputs are 0.0/1.0).
//
// R5 theory: R4's 3-barrier phase structure made traffic bursty + vmcnt(0)
// drains at each barrier (74% of the 287MB/6.29TB/s floor). Barrier-free
// waves stream like a copy kernel. launch_bounds(256,4) keeps 12-load MLP.

typedef float f4 __attribute__((ext_vector_type(4)));

#define WAVES 4               // independent waves per block
#define BPW 4                 // batches per wave
#define NF4W 729              // f4 per wave (BPW*729/4)
#define ROWSW 324             // row words per wave (BPW*81)

// wave-internal LDS fence: order ds_write -> ds_read across lanes of one wave.
// sched_barrier(0) pins the compiler (rule #18); s_waitcnt drains LDS queue.
#define WAVE_FENCE() do {                                   \
    __builtin_amdgcn_sched_barrier(0);                      \
    asm volatile("s_waitcnt lgkmcnt(0)" ::: "memory");      \
    __builtin_amdgcn_sched_barrier(0);                      \
} while (0)

__global__ __launch_bounds__(256, 4) void sudoku_hbox_kernel(
    const float* __restrict__ in, float* __restrict__ out, int B) {
    __shared__ unsigned char m4s[WAVES][736];     // nibble per f4 (+pad)
    __shared__ unsigned rowb[WAVES][ROWSW + 2];   // 9-bit row words (+pad)

    const int tid  = threadIdx.x;
    const int w    = tid >> 6;
    const int lane = tid & 63;
    const long long wbase4 = ((long long)blockIdx.x * WAVES + w) * NF4W;
    const f4* gin  = (const f4*)in + wbase4;
    f4* gout       = (f4*)out + wbase4;
    unsigned char* my4  = m4s[w];
    unsigned*      myrow = rowb[w];

    // ---- 1) loads (12 in flight) -> nibble bytes ----
    f4 v[12];
    #pragma unroll
    for (int i = 0; i < 12; ++i) {
        int idx = lane + 64 * i;
        if (idx < NF4W) v[i] = gin[idx];
    }
    #pragma unroll
    for (int i = 0; i < 12; ++i) {
        int idx = lane + 64 * i;
        if (idx < NF4W) {
            unsigned m = (v[i].x > 0.5f ? 1u : 0u) | (v[i].y > 0.5f ? 2u : 0u) |
                         (v[i].z > 0.5f ? 4u : 0u) | (v[i].w > 0.5f ? 8u : 0u);
            my4[idx] = (unsigned char)m;
        }
    }
    WAVE_FENCE();

    // ---- 2) lanes 0..35: solve one (bl,h) unit in registers ----
    if (lane < BPW * 9) {
        const int bl = lane / 9;
        const int h  = lane - bl * 9;
        unsigned rows[9], uniqm = 0;
        #pragma unroll
        for (int c = 0; c < 9; ++c) {
            int r  = bl * 81 + c * 9 + h;
            int f0 = 9 * r;
            int a  = f0 & 3;
            int j0 = f0 >> 2;
            unsigned win = ((unsigned)my4[j0] >> a) |
                           ((unsigned)my4[j0 + 1] << (4 - a)) |
                           ((unsigned)my4[j0 + 2] << (8 - a));
            rows[c] = win & 0x1FFu;
            if (__popc(rows[c]) == 1) uniqm |= (1u << c);
        }
        unsigned covered = 0;
        #pragma unroll
        for (int c = 0; c < 9; ++c)
            covered |= ((uniqm >> c) & 1u) ? rows[c] : 0u;
        #pragma unroll
        for (int c = 0; c < 9; ++c) {
            unsigned ob = ((uniqm >> c) & 1u) ? rows[c] : (rows[c] & ~covered);
            myrow[bl * 81 + c * 9 + h] = ob;
        }
    }
    WAVE_FENCE();

    // ---- 3) expand row words -> f4, nt store ----
    #pragma unroll
    for (int i = 0; i < 12; ++i) {
        int idx = lane + 64 * i;
        if (idx < NF4W) {
            int o  = idx * 4;
            int r0 = o / 9;
            int w0 = o - r0 * 9;
            unsigned v0 = myrow[r0];
            unsigned v1 = myrow[r0 + 1];          // pad word; bits masked below
            unsigned win = (v0 >> w0) | (v1 << (9 - w0));
            f4 ov;
            ov.x = (win & 1u) ? 1.0f : 0.0f;
            ov.y = (win & 2u) ? 1.0f : 0.0f;
            ov.z = (win & 4u) ? 1.0f : 0.0f;
            ov.w = (win & 8u) ? 1.0f : 0.0f;
            __builtin_nontemporal_store(ov, &gout[idx]);
        }
    }
}

extern "C" void kernel_launch(void* const* d_in, const int* in_sizes, int n_in,
                              void* d_out, int out_size, void* d_ws, size_t ws_size,
                              hipStream_t stream) {
    const float* in = (const float*)d_in[0];
    float* out = (float*)d_out;
    const int total = in_sizes[0];
    const int B = total / 729;                         // 65536
    const int nblk = (B + WAVES * BPW - 1) / (WAVES * BPW);  // 4096
    hipLaunchKernelGGL(sudoku_hbox_kernel, dim3(nblk), dim3(256), 0, stream,
                       in, out, B);
}